// Round 2
// baseline (35.078 us; speedup 1.0000x reference)
//
#include <hip/hip_runtime.h>

#define N_ATOMS 512
#define N_PAIRS 130816            // 512*511/2
#define N_GROUPS (N_PAIRS / 4)    // 32704 float4 groups per batch
#define BATCH 128

typedef float f32x4 __attribute__((ext_vector_type(4)));

// AU2KCALMOLA / MAX_NRF, computed in double then narrowed once.
constexpr float SCALE = (float)(627.5095 * 0.529177 / 100.0);

// Row index i (>=1) such that i*(i-1)/2 <= p < i*(i+1)/2.
__device__ __forceinline__ int row_of_pair(int p) {
    float fp = (float)p;
    int i = (int)((1.0f + sqrtf(1.0f + 8.0f * fp)) * 0.5f);
    // 1-ulp sqrt error -> at most off by one; fix up.
    if ((i * (i - 1)) / 2 > p) --i;
    else if ((i * (i + 1)) / 2 <= p) ++i;
    return i;
}

__global__ __launch_bounds__(256) void coords_to_nrf_kernel(
    const float* __restrict__ coords,   // [B, 512, 3]
    const float* __restrict__ atom_nc,  // [B, N_PAIRS]
    float* __restrict__ out)            // [B, N_PAIRS]
{
    const int b = blockIdx.y;
    const int g = blockIdx.x * blockDim.x + threadIdx.x;  // 4-pair group
    if (g >= N_GROUPS) return;

    const int p0 = g * 4;
    const float* cb = coords + (size_t)b * (N_ATOMS * 3);

    // Streaming load of atom_nc (read-once -> nontemporal).
    const f32x4* anc4 = reinterpret_cast<const f32x4*>(atom_nc + (size_t)b * N_PAIRS);
    f32x4 a4 = __builtin_nontemporal_load(&anc4[g]);

    int i = row_of_pair(p0);
    int j = p0 - (i * (i - 1)) / 2;

    f32x4 res;
#pragma unroll
    for (int k = 0; k < 4; ++k) {
        float xi = cb[3 * i + 0], yi = cb[3 * i + 1], zi = cb[3 * i + 2];
        float xj = cb[3 * j + 0], yj = cb[3 * j + 1], zj = cb[3 * j + 2];
        float dx = xi - xj, dy = yi - yj, dz = zi - zj;
        float d2 = dx * dx + dy * dy + dz * dz;
        res[k] = a4[k] * (SCALE / d2);
        // Advance to next pair: j++ with carry into next row.
        if (++j == i) { ++i; j = 0; }
    }

    f32x4* out4 = reinterpret_cast<f32x4*>(out + (size_t)b * N_PAIRS);
    __builtin_nontemporal_store(res, &out4[g]);
}

extern "C" void kernel_launch(void* const* d_in, const int* in_sizes, int n_in,
                              void* d_out, int out_size, void* d_ws, size_t ws_size,
                              hipStream_t stream) {
    const float* coords  = (const float*)d_in[0];  // [128, 512, 3] f32
    const float* atom_nc = (const float*)d_in[1];  // [128, 130816] f32
    float* out = (float*)d_out;                    // [128, 130816] f32

    dim3 block(256);
    dim3 grid((N_GROUPS + 255) / 256, BATCH);      // 128 x 128 blocks
    coords_to_nrf_kernel<<<grid, block, 0, stream>>>(coords, atom_nc, out);
}